// Round 7
// baseline (226.154 us; speedup 1.0000x reference)
//
#include <hip/hip_runtime.h>
#include <stdint.h>

// B=4, n=8192, d=512.  Algebraic form:
//   G_b = X_b^T X_b                       [512,512] sym, K=8192
//   kvt_b = Wv * (G_b*scale) * Wth^T      [e][d], scale = 1/(n*sqrt(d))
//   meanV_b[e] = colmean(X_b) . Wv[e][:]
//   out = X_b @ kvt_b(B-layout) + meanV
// Round 7: Xt eliminated; G GEMM reads row-major Xb via ds_read_b64_tr_b16.
// tr semantics (m156/m162-coherent): lane fetches 4 CONTIGUOUS bf16 at its own
// vaddr; each 16-lane group's 128B = 4x16 row-major tile T; delivered(l,j) =
// T[j][l&15].  So per-lane vaddr = subtile_base + l16*8 (group covers the
// subtile), NOT a strided gather — this was round 6's bug (l16*2).

typedef __bf16 bf16x8 __attribute__((ext_vector_type(8)));
typedef float f32x4 __attribute__((ext_vector_type(4)));
typedef unsigned short u16x4 __attribute__((ext_vector_type(4)));
typedef unsigned short u16x8 __attribute__((ext_vector_type(8)));
typedef unsigned int u32x2 __attribute__((ext_vector_type(2)));

#define BK 32

#define BAR asm volatile("s_barrier" ::: "memory")

template <int N>
__device__ __forceinline__ void vmw() {
  static_assert(N == 0 || N == 1 || N == 2 || N == 4 || N == 8, "vmw");
  if constexpr (N == 0) asm volatile("s_waitcnt vmcnt(0)" ::: "memory");
  else if constexpr (N == 1) asm volatile("s_waitcnt vmcnt(1)" ::: "memory");
  else if constexpr (N == 2) asm volatile("s_waitcnt vmcnt(2)" ::: "memory");
  else if constexpr (N == 4) asm volatile("s_waitcnt vmcnt(4)" ::: "memory");
  else if constexpr (N == 8) asm volatile("s_waitcnt vmcnt(8)" ::: "memory");
}

__device__ __forceinline__ unsigned short f2bf(float f) {
  union { float f; unsigned int u; } c; c.f = f;
  unsigned int u = c.u;
  return (unsigned short)((u + 0x7FFFu + ((u >> 16) & 1u)) >> 16);  // RNE
}
__device__ __forceinline__ float bf2f(unsigned short h) {
  union { unsigned int u; float f; } c; c.u = ((unsigned int)h) << 16;
  return c.f;
}

__device__ __forceinline__ void gld16(const void* g, void* l) {
  using gptr_t = const __attribute__((address_space(1))) void*;
  using lptr_t = __attribute__((address_space(3))) void*;
  __builtin_amdgcn_global_load_lds((gptr_t)(uintptr_t)g,
                                   (lptr_t)(uint32_t)(uintptr_t)l, 16, 0, 0);
}

// ---------------- K-inner tile GEMM core (rm/out kernels) -------------------
// TBxTB, K=512: C[m][n] = sum_k A[m0+m][k] * B[n0+n][k].  3-buffer pipeline,
// counted vmcnt; 16-B granule XOR swizzle (pre-swizzled global src + swizzled
// ds_read) kills the 8-way bank conflict; setprio around MFMA cluster.
template <int TB, bool SAME>
__device__ __forceinline__ void gemm_tile(const unsigned short* __restrict__ A, int lda,
                                          const unsigned short* __restrict__ B, int ldb,
                                          int m0, int n0, f32x4 (&acc)[TB / 32][TB / 32]) {
  static_assert(TB == 64 || TB == 128, "TB");
  constexpr int FR = TB / 32;
  constexpr int LJ = (TB * 4) / 256;
  constexpr int LPS = SAME ? LJ : 2 * LJ;
  constexpr int NK = 512 / BK;
  __shared__ unsigned short sA[3][TB * BK];
  __shared__ unsigned short sB[3][TB * BK];
  const int tid = threadIdx.x;
  const int lane = tid & 63;
  const int w = tid >> 6;
  const int wm = w >> 1, wn = w & 1;
  const int quad = lane >> 4, l16 = lane & 15;
  const int sq = (quad ^ ((l16 >> 1) & 3)) * 8;

#pragma unroll
  for (int mi = 0; mi < FR; mi++)
#pragma unroll
    for (int ni = 0; ni < FR; ni++) acc[mi][ni] = f32x4{0.f, 0.f, 0.f, 0.f};

  auto stage = [&](int bb, int kt) {
    const int kk = kt * BK;
#pragma unroll
    for (int j = 0; j < LJ; j++) {
      const int slot = w * (LJ * 64) + j * 64 + lane;
      const int row = slot >> 2;
      const int col = ((slot & 3) ^ ((slot >> 3) & 3)) * 8;
      const int basegr = w * (LJ * 64) + j * 64;
      gld16(A + (size_t)(m0 + row) * lda + kk + col, (char*)sA[bb] + (size_t)basegr * 16);
      if constexpr (!SAME)
        gld16(B + (size_t)(n0 + row) * ldb + kk + col, (char*)sB[bb] + (size_t)basegr * 16);
    }
  };

  auto compute = [&](int bb) {
    const unsigned short* as = sA[bb];
    const unsigned short* bs = SAME ? sA[bb] : sB[bb];
    bf16x8 af[FR], bfr[FR];
#pragma unroll
    for (int mi = 0; mi < FR; mi++)
      af[mi] = *(const bf16x8*)&as[(wm * (TB / 2) + mi * 16 + l16) * BK + sq];
#pragma unroll
    for (int ni = 0; ni < FR; ni++)
      bfr[ni] = *(const bf16x8*)&bs[(wn * (TB / 2) + ni * 16 + l16) * BK + sq];
    __builtin_amdgcn_s_setprio(1);
#pragma unroll
    for (int mi = 0; mi < FR; mi++)
#pragma unroll
      for (int ni = 0; ni < FR; ni++)
        acc[mi][ni] = __builtin_amdgcn_mfma_f32_16x16x32_bf16(af[mi], bfr[ni],
                                                              acc[mi][ni], 0, 0, 0);
    __builtin_amdgcn_s_setprio(0);
  };

  stage(0, 0);
  stage(1, 1);
  stage(2, 2);
#pragma unroll
  for (int kt = 0; kt < NK; ++kt) {
    if (kt < NK - 2) { vmw<2 * LPS>(); }
    else if (kt == NK - 2) { vmw<LPS>(); }
    else { vmw<0>(); }
    BAR;
    compute(kt % 3);
    BAR;
    if (kt < NK - 3) stage(kt % 3, kt + 3);
  }
}

// ------------- N-inner (transpose-read) tile GEMM core for G ----------------
// A and B are both slices of row-major Xs[n][512] (n is the K dim, 512 rows).
// Per K-step: stage [32 n][128 d] into LDS as [dblk 8][nblk 8][4 n][16 d]
// subtiles (per-lane global src, linear LDS dest).  Read: per-lane vaddr =
// subtile_base + quad*256 + l16*8 (+mi*1024); the 16-lane group fetches the
// whole 128B subtile row-major, HW transpose delivers lane l16 elem j =
// T[j][l16] = X[n = kt*32 + quad*8 + j][d = m0 + dblk*16 + l16]; offset:128
// gives n = quad*8 + 4..7.  d-mapping exact (m156 column-select); k-order is
// the same function of (quad,j) for A and B so any k-permutation cancels.
template <bool SAME>
__device__ __forceinline__ void gemm_tile_nt(const unsigned short* __restrict__ Xs,
                                             int m0, int n0, f32x4 (&acc)[4][4]) {
  constexpr int LPS = SAME ? 2 : 4;
  constexpr int NK = 16;
  __shared__ unsigned short sA[3][128 * BK];
  __shared__ unsigned short sB[3][128 * BK];
  const int tid = threadIdx.x;
  const int lane = tid & 63;
  const int w = tid >> 6;
  const int wm = w >> 1, wn = w & 1;
  const int quad = lane >> 4, l16 = lane & 15;

#pragma unroll
  for (int mi = 0; mi < 4; mi++)
#pragma unroll
    for (int ni = 0; ni < 4; ni++) acc[mi][ni] = f32x4{0.f, 0.f, 0.f, 0.f};

  auto stage = [&](int bb, int kt) {
#pragma unroll
    for (int j = 0; j < 2; j++) {
      const int g = w * 128 + j * 64 + lane;   // LDS granule 0..511
      const int dblk = g >> 6;
      const int nblk = (g >> 3) & 7;
      const int nr = (g >> 1) & 3;
      const int half = g & 1;
      const int n = kt * 32 + nblk * 4 + nr;
      const int base = w * 128 + j * 64;       // wave-uniform LDS base
      gld16(Xs + (size_t)n * 512 + m0 + dblk * 16 + half * 8,
            (char*)sA[bb] + (size_t)base * 16);
      if constexpr (!SAME)
        gld16(Xs + (size_t)n * 512 + n0 + dblk * 16 + half * 8,
              (char*)sB[bb] + (size_t)base * 16);
    }
  };

  auto compute = [&](int bb) {
    // per-lane vaddr: group-lane l16 covers the 128B subtile at l16*8 (FIX:
    // was l16*2 in round 6 — strided-gather misread of the tr semantics)
    const unsigned int abase =
        (unsigned int)(uintptr_t)(&sA[bb][0]) + (unsigned int)(quad * 256 + l16 * 8);
    const unsigned int bbase =
        (SAME ? (unsigned int)(uintptr_t)(&sA[bb][0])
              : (unsigned int)(uintptr_t)(&sB[bb][0])) +
        (unsigned int)(quad * 256 + l16 * 8);
    u32x2 ra[4][2], rb[4][2];
#pragma unroll
    for (int mi = 0; mi < 4; mi++) {
      const unsigned int pa = abase + (unsigned int)((wm * 4 + mi) * 1024);
      asm volatile("ds_read_b64_tr_b16 %0, %1" : "=v"(ra[mi][0]) : "v"(pa));
      asm volatile("ds_read_b64_tr_b16 %0, %1 offset:128" : "=v"(ra[mi][1]) : "v"(pa));
    }
#pragma unroll
    for (int ni = 0; ni < 4; ni++) {
      const unsigned int pb = bbase + (unsigned int)((wn * 4 + ni) * 1024);
      asm volatile("ds_read_b64_tr_b16 %0, %1" : "=v"(rb[ni][0]) : "v"(pb));
      asm volatile("ds_read_b64_tr_b16 %0, %1 offset:128" : "=v"(rb[ni][1]) : "v"(pb));
    }
    asm volatile("s_waitcnt lgkmcnt(0)" ::: "memory");
    __builtin_amdgcn_sched_barrier(0);  // rule #18: pin consumers after the wait
    union U { unsigned int u[4]; bf16x8 v; };
    bf16x8 af[4], bfr[4];
#pragma unroll
    for (int mi = 0; mi < 4; mi++) {
      U ua;
      ua.u[0] = ra[mi][0][0]; ua.u[1] = ra[mi][0][1];
      ua.u[2] = ra[mi][1][0]; ua.u[3] = ra[mi][1][1];
      af[mi] = ua.v;
    }
#pragma unroll
    for (int ni = 0; ni < 4; ni++) {
      U ub;
      ub.u[0] = rb[ni][0][0]; ub.u[1] = rb[ni][0][1];
      ub.u[2] = rb[ni][1][0]; ub.u[3] = rb[ni][1][1];
      bfr[ni] = ub.v;
    }
    __builtin_amdgcn_s_setprio(1);
#pragma unroll
    for (int mi = 0; mi < 4; mi++)
#pragma unroll
      for (int ni = 0; ni < 4; ni++)
        acc[mi][ni] = __builtin_amdgcn_mfma_f32_16x16x32_bf16(af[mi], bfr[ni],
                                                              acc[mi][ni], 0, 0, 0);
    __builtin_amdgcn_s_setprio(0);
  };

  stage(0, 0);
  stage(1, 1);
  stage(2, 2);
#pragma unroll
  for (int kt = 0; kt < NK; ++kt) {
    if (kt < NK - 2) { vmw<2 * LPS>(); }
    else if (kt == NK - 2) { vmw<LPS>(); }
    else { vmw<0>(); }
    BAR;
    compute(kt % 3);
    BAR;
    if (kt < NK - 3) stage(kt % 3, kt + 3);
  }
}

// ---- prep: pure streaming cast X fp32 -> Xb bf16 + colsum.  No LDS/barrier.
__global__ __launch_bounds__(256) void prep_kernel(const float* __restrict__ X,
                                                   unsigned short* __restrict__ Xb,
                                                   float* __restrict__ mean_x) {
  const int t = threadIdx.x;
  const int bid = blockIdx.x;       // 1024
  const int n0 = (bid >> 3) * 256;
  const int d0 = (bid & 7) * 64;
  const int b = n0 >> 13;
  const int rg = t >> 4;            // 0..15 row group
  const int c = t & 15;             // d granule
  float cs[4] = {0.f, 0.f, 0.f, 0.f};
#pragma unroll
  for (int hb = 0; hb < 2; hb++) {
    f32x4 v[8];
#pragma unroll
    for (int i = 0; i < 8; i++) {
      const int r = rg + 16 * (hb * 8 + i);
      v[i] = *(const f32x4*)(X + (size_t)(n0 + r) * 512 + d0 + c * 4);
    }
    __builtin_amdgcn_sched_barrier(0);  // keep the batch of 8 loads in flight
#pragma unroll
    for (int i = 0; i < 8; i++) {
      const int r = rg + 16 * (hb * 8 + i);
      u16x4 o;
#pragma unroll
      for (int j = 0; j < 4; j++) o[j] = f2bf(v[i][j]);
      *(u16x4*)(Xb + (size_t)(n0 + r) * 512 + d0 + c * 4) = o;
#pragma unroll
      for (int j = 0; j < 4; j++) cs[j] += bf2f(o[j]);
    }
  }
#pragma unroll
  for (int j = 0; j < 4; j++) {
    float sv = cs[j];
    sv += __shfl_xor(sv, 16);
    sv += __shfl_xor(sv, 32);
    if ((t & 63) < 16) atomicAdd(&mean_x[b * 512 + d0 + c * 4 + j], sv);
  }
}

// ---- W casts + zero-init of mean_x (runs before prep in-stream) ----
__global__ __launch_bounds__(256) void prep_w_kernel(const float* __restrict__ Wv,
                                                     const float* __restrict__ Wth,
                                                     unsigned short* __restrict__ Wvb,
                                                     unsigned short* __restrict__ Wtb,
                                                     float* __restrict__ mean_x) {
  const int blk = blockIdx.x;
  const int t = threadIdx.x;
  if (blk == 0) {
#pragma unroll
    for (int i = 0; i < 8; i++) mean_x[t + i * 256] = 0.f;
  }
  const float* src = (blk < 128) ? Wv : Wth;
  unsigned short* dst = (blk < 128) ? Wvb : Wtb;
  const int i = (blk & 127) * 256 + t;
  const f32x4* pp = (const f32x4*)(src + (size_t)i * 8);
  f32x4 v0 = pp[0], v1 = pp[1];
  u16x8 o;
  o[0] = f2bf(v0[0]); o[1] = f2bf(v0[1]); o[2] = f2bf(v0[2]); o[3] = f2bf(v0[3]);
  o[4] = f2bf(v1[0]); o[5] = f2bf(v1[1]); o[6] = f2bf(v1[2]); o[7] = f2bf(v1[3]);
  *(u16x8*)(dst + (size_t)i * 8) = o;
}

// ---- G = X^T X (per batch) from row-major Xb, split-K=16, upper tiles ----
static __device__ const int TI[10] = {0, 0, 0, 0, 1, 1, 1, 2, 2, 3};
static __device__ const int TJ[10] = {0, 1, 2, 3, 1, 2, 3, 2, 3, 3};

__global__ __launch_bounds__(256) void g_gemm_kernel(const unsigned short* __restrict__ Xb,
                                                     float* __restrict__ G_part) {
  const int t = blockIdx.y;        // 0..9 upper tile
  const int z = blockIdx.x;        // b*16 + s
  const int b = z >> 4, s = z & 15;
  const int m0 = TI[t] * 128, n0 = TJ[t] * 128;
  const unsigned short* Xs = Xb + (size_t)(b * 8192 + s * 512) * 512;
  f32x4 acc[4][4];
  if (m0 == n0)
    gemm_tile_nt<true>(Xs, m0, n0, acc);
  else
    gemm_tile_nt<false>(Xs, m0, n0, acc);
  float* Cp = G_part + ((size_t)z * 10 + t) * 16384;  // tile stored [n_local][m_local]
  const int tid = threadIdx.x, lane = tid & 63, w = tid >> 6;
  const int wm = w >> 1, wn = w & 1, quad = lane >> 4, l16 = lane & 15;
#pragma unroll
  for (int mi = 0; mi < 4; mi++)
#pragma unroll
    for (int ni = 0; ni < 4; ni++) {
      const int ml = wm * 64 + mi * 16 + quad * 4;
      const int nl = wn * 64 + ni * 16 + l16;
      *(f32x4*)(Cp + (size_t)nl * 128 + ml) = acc[mi][ni];
    }
}

// sum slices, scale, cast bf16, write G + mirror.  Blocks >= 320: meanV part.
__global__ __launch_bounds__(256) void g_fin_kernel(const float* __restrict__ G_part,
                                                    unsigned short* __restrict__ Gb,
                                                    const float* __restrict__ mean_x,
                                                    const float* __restrict__ Wv,
                                                    float* __restrict__ meanV) {
  const int blk = blockIdx.x;  // 4*10*8 + 8
  if (blk >= 320) {
    const int idx = (blk - 320) * 256 + threadIdx.x;
    const int b = idx >> 9, e = idx & 511;
    const float* mx = mean_x + b * 512;
    const float* wr = Wv + (size_t)e * 512;
    float s = 0.f;
    for (int d = 0; d < 512; d += 4) {
      f32x4 a = *(const f32x4*)(mx + d);
      f32x4 w4 = *(const f32x4*)(wr + d);
      s += a[0] * w4[0] + a[1] * w4[1] + a[2] * w4[2] + a[3] * w4[3];
    }
    meanV[idx] = s * (1.f / 8192.f);
    return;
  }
  const int b = blk / 80, rem = blk % 80;
  const int t = rem >> 3, cc = rem & 7;
  const int i = TI[t], j = TJ[t];
  const int m0 = i * 128, n0 = j * 128;
  const int tid = threadIdx.x;
  const int np = cc * 16 + (tid >> 4);
  const int mp = (tid & 15) * 8;
  f32x4 s0 = f32x4{0.f, 0.f, 0.f, 0.f}, s1 = f32x4{0.f, 0.f, 0.f, 0.f};
#pragma unroll
  for (int s = 0; s < 16; s++) {
    const float* p = G_part + (((size_t)(b * 16 + s)) * 10 + t) * 16384 + (size_t)np * 128 + mp;
    s0 += *(const f32x4*)p;
    s1 += *(const f32x4*)(p + 4);
  }
  const float scale = (float)(1.0 / (8192.0 * 22.627416997969522));
  unsigned short h[8];
#pragma unroll
  for (int r = 0; r < 4; r++) { h[r] = f2bf(s0[r] * scale); h[r + 4] = f2bf(s1[r] * scale); }
  unsigned short* Gbb = Gb + (size_t)b * 262144;
#pragma unroll
  for (int r = 0; r < 8; r++)
    Gbb[(size_t)(m0 + mp + r) * 512 + (n0 + np)] = h[r];
  if (i != j) {
    u16x8 o;
#pragma unroll
    for (int r = 0; r < 8; r++) o[r] = h[r];
    *(u16x8*)(Gbb + (size_t)(n0 + np) * 512 + (m0 + mp)) = o;
  }
}

// small batched GEMM, row-major bf16 C: C[m][n] = sum_k A[m][k]B[n][k], all 512.
__global__ __launch_bounds__(256) void gemm_rm_kernel(const unsigned short* __restrict__ A,
                                                      const unsigned short* __restrict__ B,
                                                      unsigned short* __restrict__ C,
                                                      size_t Abs, size_t Bbs) {
  const int b = blockIdx.z;
  const int m0 = blockIdx.x * 64, n0 = blockIdx.y * 64;
  f32x4 acc[2][2];
  gemm_tile<64, false>(A + (size_t)b * Abs, 512, B + (size_t)b * Bbs, 512, m0, n0, acc);
  unsigned short* Cb = C + (size_t)b * 262144;
  const int tid = threadIdx.x, lane = tid & 63, w = tid >> 6;
  const int wm = w >> 1, wn = w & 1, quad = lane >> 4, l16 = lane & 15;
#pragma unroll
  for (int mi = 0; mi < 2; mi++)
#pragma unroll
    for (int ni = 0; ni < 2; ni++) {
      const int m = m0 + wm * 32 + mi * 16 + quad * 4;
      const int n = n0 + wn * 32 + ni * 16 + l16;
#pragma unroll
      for (int r = 0; r < 4; r++)
        Cb[(size_t)(m + r) * 512 + n] = f2bf(acc[mi][ni][r]);
    }
}

// final: out[m][e] = sum_d Xb[m][d]*kvt_b[e][d] + meanV[b][e]
__global__ __launch_bounds__(256) void gemm_out_kernel(
    const unsigned short* __restrict__ Xb, const unsigned short* __restrict__ kvt,
    const float* __restrict__ meanV, float* __restrict__ out) {
  const int D = blockIdx.x;                      // 0..1023
  const int gm = (D & 7) + ((D >> 5) << 3);      // m-tile 0..255
  const int nt = (D >> 3) & 3;                   // n-tile 0..3
  const int m0 = gm * 128, n0 = nt * 128;
  const int b = gm >> 6;
  const unsigned short* Bm = kvt + (size_t)b * 262144;
  f32x4 acc[4][4];
  gemm_tile<128, false>(Xb, 512, Bm, 512, m0, n0, acc);
  const int tid = threadIdx.x, lane = tid & 63, w = tid >> 6;
  const int wm = w >> 1, wn = w & 1, quad = lane >> 4, l16 = lane & 15;
#pragma unroll
  for (int ni = 0; ni < 4; ni++) {
    const int e = n0 + wn * 64 + ni * 16 + l16;
    const float mu = meanV[b * 512 + e];
#pragma unroll
    for (int mi = 0; mi < 4; mi++) {
      const int m = m0 + wm * 64 + mi * 16 + quad * 4;
#pragma unroll
      for (int r = 0; r < 4; r++)
        out[(size_t)(m + r) * 512 + e] = acc[mi][ni][r] + mu;
    }
  }
}

extern "C" void kernel_launch(void* const* d_in, const int* in_sizes, int n_in,
                              void* d_out, int out_size, void* d_ws, size_t ws_size,
                              hipStream_t stream) {
  const float* X = (const float*)d_in[0];
  const float* Wv = (const float*)d_in[1];
  const float* Wth = (const float*)d_in[2];
  float* out = (float*)d_out;
  char* ws = (char*)d_ws;

  unsigned short* Xb = (unsigned short*)(ws);                  // 32 MB
  float* G_part = (float*)(ws + 67108864ull);                  // 41.94 MB
  unsigned short* Gb = (unsigned short*)(ws + 109051904ull);   // 2 MB
  unsigned short* Ht = (unsigned short*)(ws + 111149056ull);   // 2 MB
  unsigned short* kvt = (unsigned short*)(ws + 113246208ull);  // 2 MB
  unsigned short* Wvb = (unsigned short*)(ws + 115343360ull);  // 0.5 MB
  unsigned short* Wtb = (unsigned short*)(ws + 115867648ull);  // 0.5 MB
  float* mean_x = (float*)(ws + 116391936ull);                 // 8 KB
  float* meanV = (float*)(ws + 116400128ull);                  // 8 KB

  prep_w_kernel<<<256, 256, 0, stream>>>(Wv, Wth, Wvb, Wtb, mean_x);
  prep_kernel<<<1024, 256, 0, stream>>>(X, Xb, mean_x);

  g_gemm_kernel<<<dim3(64, 10), 256, 0, stream>>>(Xb, G_part);
  g_fin_kernel<<<328, 256, 0, stream>>>(G_part, Gb, mean_x, Wv, meanV);

  gemm_rm_kernel<<<dim3(8, 8, 4), 256, 0, stream>>>(Wvb, Gb, Ht, 0, 262144);
  gemm_rm_kernel<<<dim3(8, 8, 4), 256, 0, stream>>>(Ht, Wtb, kvt, 262144, 0);

  gemm_out_kernel<<<1024, 256, 0, stream>>>(Xb, kvt, meanV, out);
}

// Round 8
// 224.357 us; speedup vs baseline: 1.0080x; 1.0080x over previous
//
#include <hip/hip_runtime.h>
#include <stdint.h>

// B=4, n=8192, d=512.  Algebraic form:
//   G_b = X_b^T X_b                       [512,512] sym, K=8192
//   kvt_b = Wv * (G_b*scale) * Wth^T      [e][d], scale = 1/(n*sqrt(d))
//   meanV_b[e] = colmean(X_b) . Wv[e][:]
//   out = X_b @ kvt_b(B-layout) + meanV
// Round 8: prep = pure streaming cast (max TLP: 2048 blocks, no LDS, no tail);
// colsum folded into g_gemm as 64 extra rider blocks (t==10) reading the same
// L2-warm Xb slices the GEMM blocks stage.  G GEMM consumes row-major Xb via
// ds_read_b64_tr_b16 (semantics verified in round 7: 16-lane group fetches a
// 128B [4n][16d] subtile row-major, HW delivers lane l the d-column l&15).

typedef __bf16 bf16x8 __attribute__((ext_vector_type(8)));
typedef float f32x4 __attribute__((ext_vector_type(4)));
typedef unsigned short u16x4 __attribute__((ext_vector_type(4)));
typedef unsigned short u16x8 __attribute__((ext_vector_type(8)));
typedef unsigned int u32x2 __attribute__((ext_vector_type(2)));

#define BK 32

#define BAR asm volatile("s_barrier" ::: "memory")

template <int N>
__device__ __forceinline__ void vmw() {
  static_assert(N == 0 || N == 1 || N == 2 || N == 4 || N == 8, "vmw");
  if constexpr (N == 0) asm volatile("s_waitcnt vmcnt(0)" ::: "memory");
  else if constexpr (N == 1) asm volatile("s_waitcnt vmcnt(1)" ::: "memory");
  else if constexpr (N == 2) asm volatile("s_waitcnt vmcnt(2)" ::: "memory");
  else if constexpr (N == 4) asm volatile("s_waitcnt vmcnt(4)" ::: "memory");
  else if constexpr (N == 8) asm volatile("s_waitcnt vmcnt(8)" ::: "memory");
}

__device__ __forceinline__ unsigned short f2bf(float f) {
  union { float f; unsigned int u; } c; c.f = f;
  unsigned int u = c.u;
  return (unsigned short)((u + 0x7FFFu + ((u >> 16) & 1u)) >> 16);  // RNE
}
__device__ __forceinline__ float bf2f(unsigned short h) {
  union { unsigned int u; float f; } c; c.u = ((unsigned int)h) << 16;
  return c.f;
}

__device__ __forceinline__ void gld16(const void* g, void* l) {
  using gptr_t = const __attribute__((address_space(1))) void*;
  using lptr_t = __attribute__((address_space(3))) void*;
  __builtin_amdgcn_global_load_lds((gptr_t)(uintptr_t)g,
                                   (lptr_t)(uint32_t)(uintptr_t)l, 16, 0, 0);
}

// ---------------- K-inner tile GEMM core (rm/out kernels) -------------------
// TBxTB, K=512: C[m][n] = sum_k A[m0+m][k] * B[n0+n][k].  3-buffer pipeline,
// counted vmcnt; 16-B granule XOR swizzle (pre-swizzled global src + swizzled
// ds_read) kills the 8-way bank conflict; setprio around MFMA cluster.
template <int TB, bool SAME>
__device__ __forceinline__ void gemm_tile(const unsigned short* __restrict__ A, int lda,
                                          const unsigned short* __restrict__ B, int ldb,
                                          int m0, int n0, f32x4 (&acc)[TB / 32][TB / 32]) {
  static_assert(TB == 64 || TB == 128, "TB");
  constexpr int FR = TB / 32;
  constexpr int LJ = (TB * 4) / 256;
  constexpr int LPS = SAME ? LJ : 2 * LJ;
  constexpr int NK = 512 / BK;
  __shared__ unsigned short sA[3][TB * BK];
  __shared__ unsigned short sB[3][TB * BK];
  const int tid = threadIdx.x;
  const int lane = tid & 63;
  const int w = tid >> 6;
  const int wm = w >> 1, wn = w & 1;
  const int quad = lane >> 4, l16 = lane & 15;
  const int sq = (quad ^ ((l16 >> 1) & 3)) * 8;

#pragma unroll
  for (int mi = 0; mi < FR; mi++)
#pragma unroll
    for (int ni = 0; ni < FR; ni++) acc[mi][ni] = f32x4{0.f, 0.f, 0.f, 0.f};

  auto stage = [&](int bb, int kt) {
    const int kk = kt * BK;
#pragma unroll
    for (int j = 0; j < LJ; j++) {
      const int slot = w * (LJ * 64) + j * 64 + lane;
      const int row = slot >> 2;
      const int col = ((slot & 3) ^ ((slot >> 3) & 3)) * 8;
      const int basegr = w * (LJ * 64) + j * 64;
      gld16(A + (size_t)(m0 + row) * lda + kk + col, (char*)sA[bb] + (size_t)basegr * 16);
      if constexpr (!SAME)
        gld16(B + (size_t)(n0 + row) * ldb + kk + col, (char*)sB[bb] + (size_t)basegr * 16);
    }
  };

  auto compute = [&](int bb) {
    const unsigned short* as = sA[bb];
    const unsigned short* bs = SAME ? sA[bb] : sB[bb];
    bf16x8 af[FR], bfr[FR];
#pragma unroll
    for (int mi = 0; mi < FR; mi++)
      af[mi] = *(const bf16x8*)&as[(wm * (TB / 2) + mi * 16 + l16) * BK + sq];
#pragma unroll
    for (int ni = 0; ni < FR; ni++)
      bfr[ni] = *(const bf16x8*)&bs[(wn * (TB / 2) + ni * 16 + l16) * BK + sq];
    __builtin_amdgcn_s_setprio(1);
#pragma unroll
    for (int mi = 0; mi < FR; mi++)
#pragma unroll
      for (int ni = 0; ni < FR; ni++)
        acc[mi][ni] = __builtin_amdgcn_mfma_f32_16x16x32_bf16(af[mi], bfr[ni],
                                                              acc[mi][ni], 0, 0, 0);
    __builtin_amdgcn_s_setprio(0);
  };

  stage(0, 0);
  stage(1, 1);
  stage(2, 2);
#pragma unroll
  for (int kt = 0; kt < NK; ++kt) {
    if (kt < NK - 2) { vmw<2 * LPS>(); }
    else if (kt == NK - 2) { vmw<LPS>(); }
    else { vmw<0>(); }
    BAR;
    compute(kt % 3);
    BAR;
    if (kt < NK - 3) stage(kt % 3, kt + 3);
  }
}

// ------------- N-inner (transpose-read) tile GEMM core for G ----------------
// A and B are both slices of row-major Xs[n][512] (n is the K dim, 512 rows).
// Per K-step: stage [32 n][128 d] into LDS as [dblk 8][nblk 8][4 n][16 d]
// subtiles (per-lane global src, linear LDS dest).  Read: per-lane vaddr =
// subtile_base + quad*256 + l16*8 (+mi*1024); the 16-lane group fetches the
// whole 128B subtile row-major, HW transpose delivers lane l16 elem j =
// T[j][l16] = X[n = kt*32 + quad*8 + j][d = m0 + dblk*16 + l16]; offset:128
// gives n = quad*8 + 4..7.  d-mapping exact; k-order identical for A and B so
// any k-permutation cancels in the contraction.
template <bool SAME>
__device__ __forceinline__ void gemm_tile_nt(const unsigned short* __restrict__ Xs,
                                             int m0, int n0, f32x4 (&acc)[4][4]) {
  constexpr int LPS = SAME ? 2 : 4;
  constexpr int NK = 16;
  __shared__ unsigned short sA[3][128 * BK];
  __shared__ unsigned short sB[3][128 * BK];
  const int tid = threadIdx.x;
  const int lane = tid & 63;
  const int w = tid >> 6;
  const int wm = w >> 1, wn = w & 1;
  const int quad = lane >> 4, l16 = lane & 15;

#pragma unroll
  for (int mi = 0; mi < 4; mi++)
#pragma unroll
    for (int ni = 0; ni < 4; ni++) acc[mi][ni] = f32x4{0.f, 0.f, 0.f, 0.f};

  auto stage = [&](int bb, int kt) {
#pragma unroll
    for (int j = 0; j < 2; j++) {
      const int g = w * 128 + j * 64 + lane;   // LDS granule 0..511
      const int dblk = g >> 6;
      const int nblk = (g >> 3) & 7;
      const int nr = (g >> 1) & 3;
      const int half = g & 1;
      const int n = kt * 32 + nblk * 4 + nr;
      const int base = w * 128 + j * 64;       // wave-uniform LDS base
      gld16(Xs + (size_t)n * 512 + m0 + dblk * 16 + half * 8,
            (char*)sA[bb] + (size_t)base * 16);
      if constexpr (!SAME)
        gld16(Xs + (size_t)n * 512 + n0 + dblk * 16 + half * 8,
              (char*)sB[bb] + (size_t)base * 16);
    }
  };

  auto compute = [&](int bb) {
    const unsigned int abase =
        (unsigned int)(uintptr_t)(&sA[bb][0]) + (unsigned int)(quad * 256 + l16 * 8);
    const unsigned int bbase =
        (SAME ? (unsigned int)(uintptr_t)(&sA[bb][0])
              : (unsigned int)(uintptr_t)(&sB[bb][0])) +
        (unsigned int)(quad * 256 + l16 * 8);
    u32x2 ra[4][2], rb[4][2];
#pragma unroll
    for (int mi = 0; mi < 4; mi++) {
      const unsigned int pa = abase + (unsigned int)((wm * 4 + mi) * 1024);
      asm volatile("ds_read_b64_tr_b16 %0, %1" : "=v"(ra[mi][0]) : "v"(pa));
      asm volatile("ds_read_b64_tr_b16 %0, %1 offset:128" : "=v"(ra[mi][1]) : "v"(pa));
    }
#pragma unroll
    for (int ni = 0; ni < 4; ni++) {
      const unsigned int pb = bbase + (unsigned int)((wn * 4 + ni) * 1024);
      asm volatile("ds_read_b64_tr_b16 %0, %1" : "=v"(rb[ni][0]) : "v"(pb));
      asm volatile("ds_read_b64_tr_b16 %0, %1 offset:128" : "=v"(rb[ni][1]) : "v"(pb));
    }
    asm volatile("s_waitcnt lgkmcnt(0)" ::: "memory");
    __builtin_amdgcn_sched_barrier(0);  // rule #18: pin consumers after the wait
    union U { unsigned int u[4]; bf16x8 v; };
    bf16x8 af[4], bfr[4];
#pragma unroll
    for (int mi = 0; mi < 4; mi++) {
      U ua;
      ua.u[0] = ra[mi][0][0]; ua.u[1] = ra[mi][0][1];
      ua.u[2] = ra[mi][1][0]; ua.u[3] = ra[mi][1][1];
      af[mi] = ua.v;
    }
#pragma unroll
    for (int ni = 0; ni < 4; ni++) {
      U ub;
      ub.u[0] = rb[ni][0][0]; ub.u[1] = rb[ni][0][1];
      ub.u[2] = rb[ni][1][0]; ub.u[3] = rb[ni][1][1];
      bfr[ni] = ub.v;
    }
    __builtin_amdgcn_s_setprio(1);
#pragma unroll
    for (int mi = 0; mi < 4; mi++)
#pragma unroll
      for (int ni = 0; ni < 4; ni++)
        acc[mi][ni] = __builtin_amdgcn_mfma_f32_16x16x32_bf16(af[mi], bfr[ni],
                                                              acc[mi][ni], 0, 0, 0);
    __builtin_amdgcn_s_setprio(0);
  };

  stage(0, 0);
  stage(1, 1);
  stage(2, 2);
#pragma unroll
  for (int kt = 0; kt < NK; ++kt) {
    if (kt < NK - 2) { vmw<2 * LPS>(); }
    else if (kt == NK - 2) { vmw<LPS>(); }
    else { vmw<0>(); }
    BAR;
    compute(kt % 3);
    BAR;
    if (kt < NK - 3) stage(kt % 3, kt + 3);
  }
}

// ---- prep: PURE streaming cast X fp32 -> Xb bf16.  Max TLP: 2048 blocks
// (32 waves/CU resident), zero LDS, zero atomics, zero tail.  8 independent
// 16B loads in flight per thread; 16B stores.  Nothing else.
__global__ __launch_bounds__(256) void prep_kernel(const float* __restrict__ X,
                                                   unsigned short* __restrict__ Xb) {
  const int t = threadIdx.x;
  const size_t base = (size_t)blockIdx.x * 8192;   // 2048 blocks x 8192 elems
  f32x4 v[8];
#pragma unroll
  for (int k = 0; k < 4; k++) {
    const size_t idx = base + (size_t)k * 2048 + (size_t)t * 8;
    v[2 * k] = *(const f32x4*)(X + idx);
    v[2 * k + 1] = *(const f32x4*)(X + idx + 4);
  }
  __builtin_amdgcn_sched_barrier(0);  // all 8 loads issued before any use
#pragma unroll
  for (int k = 0; k < 4; k++) {
    const size_t idx = base + (size_t)k * 2048 + (size_t)t * 8;
    u16x8 o;
#pragma unroll
    for (int j = 0; j < 4; j++) o[j] = f2bf(v[2 * k][j]);
#pragma unroll
    for (int j = 0; j < 4; j++) o[4 + j] = f2bf(v[2 * k + 1][j]);
    *(u16x8*)(Xb + idx) = o;
  }
}

// ---- W casts + zero-init of mean_x (runs before prep/g_gemm in-stream) ----
__global__ __launch_bounds__(256) void prep_w_kernel(const float* __restrict__ Wv,
                                                     const float* __restrict__ Wth,
                                                     unsigned short* __restrict__ Wvb,
                                                     unsigned short* __restrict__ Wtb,
                                                     float* __restrict__ mean_x) {
  const int blk = blockIdx.x;
  const int t = threadIdx.x;
  if (blk == 0) {
#pragma unroll
    for (int i = 0; i < 8; i++) mean_x[t + i * 256] = 0.f;
  }
  const float* src = (blk < 128) ? Wv : Wth;
  unsigned short* dst = (blk < 128) ? Wvb : Wtb;
  const int i = (blk & 127) * 256 + t;
  const f32x4* pp = (const f32x4*)(src + (size_t)i * 8);
  f32x4 v0 = pp[0], v1 = pp[1];
  u16x8 o;
  o[0] = f2bf(v0[0]); o[1] = f2bf(v0[1]); o[2] = f2bf(v0[2]); o[3] = f2bf(v0[3]);
  o[4] = f2bf(v1[0]); o[5] = f2bf(v1[1]); o[6] = f2bf(v1[2]); o[7] = f2bf(v1[3]);
  *(u16x8*)(dst + (size_t)i * 8) = o;
}

// ---- G = X^T X (per batch) from row-major Xb, split-K=16, upper tiles ----
// Grid (64, 11): t<10 = GEMM tiles; t==10 = colsum rider block for slice z
// (reads the same L2-warm Xb slice, accumulates column sums, 64 atomics/addr).
static __device__ const int TI[10] = {0, 0, 0, 0, 1, 1, 1, 2, 2, 3};
static __device__ const int TJ[10] = {0, 1, 2, 3, 1, 2, 3, 2, 3, 3};

__global__ __launch_bounds__(256) void g_gemm_kernel(const unsigned short* __restrict__ Xb,
                                                     float* __restrict__ G_part,
                                                     float* __restrict__ mean_x) {
  const int t = blockIdx.y;        // 0..9 tile, 10 = colsum
  const int z = blockIdx.x;        // b*16 + s
  const int b = z >> 4, s = z & 15;
  const unsigned short* Xs = Xb + (size_t)(b * 8192 + s * 512) * 512;
  if (t == 10) {
    // colsum rider: 4 waves x 128 row-steps; lane l owns d-cols l*8..l*8+7
    const int w = threadIdx.x >> 6, l = threadIdx.x & 63;
    float cs[8] = {0.f, 0.f, 0.f, 0.f, 0.f, 0.f, 0.f, 0.f};
    for (int i0 = 0; i0 < 128; i0 += 8) {
      u16x8 val[8];
#pragma unroll
      for (int i = 0; i < 8; i++) {
        const int r = w + 4 * (i0 + i);
        val[i] = *(const u16x8*)(Xs + (size_t)r * 512 + l * 8);
      }
      __builtin_amdgcn_sched_barrier(0);
#pragma unroll
      for (int i = 0; i < 8; i++)
#pragma unroll
        for (int j = 0; j < 8; j++) cs[j] += bf2f(val[i][j]);
    }
#pragma unroll
    for (int j = 0; j < 8; j++)
      atomicAdd(&mean_x[b * 512 + l * 8 + j], cs[j]);
    return;
  }
  const int m0 = TI[t] * 128, n0 = TJ[t] * 128;
  f32x4 acc[4][4];
  if (m0 == n0)
    gemm_tile_nt<true>(Xs, m0, n0, acc);
  else
    gemm_tile_nt<false>(Xs, m0, n0, acc);
  float* Cp = G_part + ((size_t)z * 10 + t) * 16384;  // tile stored [n_local][m_local]
  const int tid = threadIdx.x, lane = tid & 63, w = tid >> 6;
  const int wm = w >> 1, wn = w & 1, quad = lane >> 4, l16 = lane & 15;
#pragma unroll
  for (int mi = 0; mi < 4; mi++)
#pragma unroll
    for (int ni = 0; ni < 4; ni++) {
      const int ml = wm * 64 + mi * 16 + quad * 4;
      const int nl = wn * 64 + ni * 16 + l16;
      *(f32x4*)(Cp + (size_t)nl * 128 + ml) = acc[mi][ni];
    }
}

// sum slices, scale, cast bf16, write G + mirror.  Blocks >= 320: meanV part.
__global__ __launch_bounds__(256) void g_fin_kernel(const float* __restrict__ G_part,
                                                    unsigned short* __restrict__ Gb,
                                                    const float* __restrict__ mean_x,
                                                    const float* __restrict__ Wv,
                                                    float* __restrict__ meanV) {
  const int blk = blockIdx.x;  // 4*10*8 + 8
  if (blk >= 320) {
    const int idx = (blk - 320) * 256 + threadIdx.x;
    const int b = idx >> 9, e = idx & 511;
    const float* mx = mean_x + b * 512;
    const float* wr = Wv + (size_t)e * 512;
    float s = 0.f;
    for (int d = 0; d < 512; d += 4) {
      f32x4 a = *(const f32x4*)(mx + d);
      f32x4 w4 = *(const f32x4*)(wr + d);
      s += a[0] * w4[0] + a[1] * w4[1] + a[2] * w4[2] + a[3] * w4[3];
    }
    meanV[idx] = s * (1.f / 8192.f);
    return;
  }
  const int b = blk / 80, rem = blk % 80;
  const int t = rem >> 3, cc = rem & 7;
  const int i = TI[t], j = TJ[t];
  const int m0 = i * 128, n0 = j * 128;
  const int tid = threadIdx.x;
  const int np = cc * 16 + (tid >> 4);
  const int mp = (tid & 15) * 8;
  f32x4 s0 = f32x4{0.f, 0.f, 0.f, 0.f}, s1 = f32x4{0.f, 0.f, 0.f, 0.f};
#pragma unroll
  for (int s = 0; s < 16; s++) {
    const float* p = G_part + (((size_t)(b * 16 + s)) * 10 + t) * 16384 + (size_t)np * 128 + mp;
    s0 += *(const f32x4*)p;
    s1 += *(const f32x4*)(p + 4);
  }
  const float scale = (float)(1.0 / (8192.0 * 22.627416997969522));
  unsigned short h[8];
#pragma unroll
  for (int r = 0; r < 4; r++) { h[r] = f2bf(s0[r] * scale); h[r + 4] = f2bf(s1[r] * scale); }
  unsigned short* Gbb = Gb + (size_t)b * 262144;
#pragma unroll
  for (int r = 0; r < 8; r++)
    Gbb[(size_t)(m0 + mp + r) * 512 + (n0 + np)] = h[r];
  if (i != j) {
    u16x8 o;
#pragma unroll
    for (int r = 0; r < 8; r++) o[r] = h[r];
    *(u16x8*)(Gbb + (size_t)(n0 + np) * 512 + (m0 + mp)) = o;
  }
}

// small batched GEMM, row-major bf16 C: C[m][n] = sum_k A[m][k]B[n][k], all 512.
__global__ __launch_bounds__(256) void gemm_rm_kernel(const unsigned short* __restrict__ A,
                                                      const unsigned short* __restrict__ B,
                                                      unsigned short* __restrict__ C,
                                                      size_t Abs, size_t Bbs) {
  const int b = blockIdx.z;
  const int m0 = blockIdx.x * 64, n0 = blockIdx.y * 64;
  f32x4 acc[2][2];
  gemm_tile<64, false>(A + (size_t)b * Abs, 512, B + (size_t)b * Bbs, 512, m0, n0, acc);
  unsigned short* Cb = C + (size_t)b * 262144;
  const int tid = threadIdx.x, lane = tid & 63, w = tid >> 6;
  const int wm = w >> 1, wn = w & 1, quad = lane >> 4, l16 = lane & 15;
#pragma unroll
  for (int mi = 0; mi < 2; mi++)
#pragma unroll
    for (int ni = 0; ni < 2; ni++) {
      const int m = m0 + wm * 32 + mi * 16 + quad * 4;
      const int n = n0 + wn * 32 + ni * 16 + l16;
#pragma unroll
      for (int r = 0; r < 4; r++)
        Cb[(size_t)(m + r) * 512 + n] = f2bf(acc[mi][ni][r]);
    }
}

// final: out[m][e] = sum_d Xb[m][d]*kvt_b[e][d] + meanV[b][e]
__global__ __launch_bounds__(256) void gemm_out_kernel(
    const unsigned short* __restrict__ Xb, const unsigned short* __restrict__ kvt,
    const float* __restrict__ meanV, float* __restrict__ out) {
  const int D = blockIdx.x;                      // 0..1023
  const int gm = (D & 7) + ((D >> 5) << 3);      // m-tile 0..255
  const int nt = (D >> 3) & 3;                   // n-tile 0..3
  const int m0 = gm * 128, n0 = nt * 128;
  const int b = gm >> 6;
  const unsigned short* Bm = kvt + (size_t)b * 262144;
  f32x4 acc[4][4];
  gemm_tile<128, false>(Xb, 512, Bm, 512, m0, n0, acc);
  const int tid = threadIdx.x, lane = tid & 63, w = tid >> 6;
  const int wm = w >> 1, wn = w & 1, quad = lane >> 4, l16 = lane & 15;
#pragma unroll
  for (int ni = 0; ni < 4; ni++) {
    const int e = n0 + wn * 64 + ni * 16 + l16;
    const float mu = meanV[b * 512 + e];
#pragma unroll
    for (int mi = 0; mi < 4; mi++) {
      const int m = m0 + wm * 64 + mi * 16 + quad * 4;
#pragma unroll
      for (int r = 0; r < 4; r++)
        out[(size_t)(m + r) * 512 + e] = acc[mi][ni][r] + mu;
    }
  }
}

extern "C" void kernel_launch(void* const* d_in, const int* in_sizes, int n_in,
                              void* d_out, int out_size, void* d_ws, size_t ws_size,
                              hipStream_t stream) {
  const float* X = (const float*)d_in[0];
  const float* Wv = (const float*)d_in[1];
  const float* Wth = (const float*)d_in[2];
  float* out = (float*)d_out;
  char* ws = (char*)d_ws;

  unsigned short* Xb = (unsigned short*)(ws);                  // 32 MB
  float* G_part = (float*)(ws + 67108864ull);                  // 41.94 MB
  unsigned short* Gb = (unsigned short*)(ws + 109051904ull);   // 2 MB
  unsigned short* Ht = (unsigned short*)(ws + 111149056ull);   // 2 MB
  unsigned short* kvt = (unsigned short*)(ws + 113246208ull);  // 2 MB
  unsigned short* Wvb = (unsigned short*)(ws + 115343360ull);  // 0.5 MB
  unsigned short* Wtb = (unsigned short*)(ws + 115867648ull);  // 0.5 MB
  float* mean_x = (float*)(ws + 116391936ull);                 // 8 KB
  float* meanV = (float*)(ws + 116400128ull);                  // 8 KB

  prep_w_kernel<<<256, 256, 0, stream>>>(Wv, Wth, Wvb, Wtb, mean_x);
  prep_kernel<<<2048, 256, 0, stream>>>(X, Xb);

  g_gemm_kernel<<<dim3(64, 11), 256, 0, stream>>>(Xb, G_part, mean_x);
  g_fin_kernel<<<328, 256, 0, stream>>>(G_part, Gb, mean_x, Wv, meanV);

  gemm_rm_kernel<<<dim3(8, 8, 4), 256, 0, stream>>>(Wvb, Gb, Ht, 0, 262144);
  gemm_rm_kernel<<<dim3(8, 8, 4), 256, 0, stream>>>(Ht, Wtb, kvt, 262144, 0);

  gemm_out_kernel<<<1024, 256, 0, stream>>>(Xb, kvt, meanV, out);
}

// Round 9
// 219.135 us; speedup vs baseline: 1.0320x; 1.0238x over previous
//
#include <hip/hip_runtime.h>
#include <stdint.h>

// B=4, n=8192, d=512.  Algebraic form:
//   G_b = X_b^T X_b                       [512,512] sym, K=8192
//   kvt_b = Wv * (G_b*scale) * Wth^T      [e][d], scale = 1/(n*sqrt(d))
//   meanV_b[e] = colmean(X_b) . Wv[e][:]
//   out = X_b @ kvt_b(B-layout) + meanV
// Round 9: g_gemm nt-core de-templatized.  Round-8 PMC showed LDS_Block_Size
// 73728: the <true>/<false> instantiations each allocated their own static
// __shared__ (24K + 48K) -> 2 blocks/CU -> 9% occupancy.  Single instance
// (always stage both, B=A on diag tiles) = 48KB -> 3 blocks/CU.

typedef __bf16 bf16x8 __attribute__((ext_vector_type(8)));
typedef float f32x4 __attribute__((ext_vector_type(4)));
typedef unsigned short u16x4 __attribute__((ext_vector_type(4)));
typedef unsigned short u16x8 __attribute__((ext_vector_type(8)));
typedef unsigned int u32x2 __attribute__((ext_vector_type(2)));

#define BK 32

#define BAR asm volatile("s_barrier" ::: "memory")

template <int N>
__device__ __forceinline__ void vmw() {
  static_assert(N == 0 || N == 1 || N == 2 || N == 4 || N == 8, "vmw");
  if constexpr (N == 0) asm volatile("s_waitcnt vmcnt(0)" ::: "memory");
  else if constexpr (N == 1) asm volatile("s_waitcnt vmcnt(1)" ::: "memory");
  else if constexpr (N == 2) asm volatile("s_waitcnt vmcnt(2)" ::: "memory");
  else if constexpr (N == 4) asm volatile("s_waitcnt vmcnt(4)" ::: "memory");
  else if constexpr (N == 8) asm volatile("s_waitcnt vmcnt(8)" ::: "memory");
}

__device__ __forceinline__ unsigned short f2bf(float f) {
  union { float f; unsigned int u; } c; c.f = f;
  unsigned int u = c.u;
  return (unsigned short)((u + 0x7FFFu + ((u >> 16) & 1u)) >> 16);  // RNE
}
__device__ __forceinline__ float bf2f(unsigned short h) {
  union { unsigned int u; float f; } c; c.u = ((unsigned int)h) << 16;
  return c.f;
}

__device__ __forceinline__ void gld16(const void* g, void* l) {
  using gptr_t = const __attribute__((address_space(1))) void*;
  using lptr_t = __attribute__((address_space(3))) void*;
  __builtin_amdgcn_global_load_lds((gptr_t)(uintptr_t)g,
                                   (lptr_t)(uint32_t)(uintptr_t)l, 16, 0, 0);
}

// ---------------- K-inner tile GEMM core (rm/out kernels) -------------------
// TBxTB, K=512: C[m][n] = sum_k A[m0+m][k] * B[n0+n][k].  3-buffer pipeline,
// counted vmcnt; 16-B granule XOR swizzle (pre-swizzled global src + swizzled
// ds_read) kills the 8-way bank conflict; setprio around MFMA cluster.
// NOTE: one instantiation per kernel only (static __shared__ is per-instance).
template <int TB>
__device__ __forceinline__ void gemm_tile(const unsigned short* __restrict__ A, int lda,
                                          const unsigned short* __restrict__ B, int ldb,
                                          int m0, int n0, f32x4 (&acc)[TB / 32][TB / 32]) {
  static_assert(TB == 64 || TB == 128, "TB");
  constexpr int FR = TB / 32;
  constexpr int LJ = (TB * 4) / 256;
  constexpr int LPS = 2 * LJ;
  constexpr int NK = 512 / BK;
  __shared__ unsigned short sA[3][TB * BK];
  __shared__ unsigned short sB[3][TB * BK];
  const int tid = threadIdx.x;
  const int lane = tid & 63;
  const int w = tid >> 6;
  const int wm = w >> 1, wn = w & 1;
  const int quad = lane >> 4, l16 = lane & 15;
  const int sq = (quad ^ ((l16 >> 1) & 3)) * 8;

#pragma unroll
  for (int mi = 0; mi < FR; mi++)
#pragma unroll
    for (int ni = 0; ni < FR; ni++) acc[mi][ni] = f32x4{0.f, 0.f, 0.f, 0.f};

  auto stage = [&](int bb, int kt) {
    const int kk = kt * BK;
#pragma unroll
    for (int j = 0; j < LJ; j++) {
      const int slot = w * (LJ * 64) + j * 64 + lane;
      const int row = slot >> 2;
      const int col = ((slot & 3) ^ ((slot >> 3) & 3)) * 8;
      const int basegr = w * (LJ * 64) + j * 64;
      gld16(A + (size_t)(m0 + row) * lda + kk + col, (char*)sA[bb] + (size_t)basegr * 16);
      gld16(B + (size_t)(n0 + row) * ldb + kk + col, (char*)sB[bb] + (size_t)basegr * 16);
    }
  };

  auto compute = [&](int bb) {
    const unsigned short* as = sA[bb];
    const unsigned short* bs = sB[bb];
    bf16x8 af[FR], bfr[FR];
#pragma unroll
    for (int mi = 0; mi < FR; mi++)
      af[mi] = *(const bf16x8*)&as[(wm * (TB / 2) + mi * 16 + l16) * BK + sq];
#pragma unroll
    for (int ni = 0; ni < FR; ni++)
      bfr[ni] = *(const bf16x8*)&bs[(wn * (TB / 2) + ni * 16 + l16) * BK + sq];
    __builtin_amdgcn_s_setprio(1);
#pragma unroll
    for (int mi = 0; mi < FR; mi++)
#pragma unroll
      for (int ni = 0; ni < FR; ni++)
        acc[mi][ni] = __builtin_amdgcn_mfma_f32_16x16x32_bf16(af[mi], bfr[ni],
                                                              acc[mi][ni], 0, 0, 0);
    __builtin_amdgcn_s_setprio(0);
  };

  stage(0, 0);
  stage(1, 1);
  stage(2, 2);
#pragma unroll
  for (int kt = 0; kt < NK; ++kt) {
    if (kt < NK - 2) { vmw<2 * LPS>(); }
    else if (kt == NK - 2) { vmw<LPS>(); }
    else { vmw<0>(); }
    BAR;
    compute(kt % 3);
    BAR;
    if (kt < NK - 3) stage(kt % 3, kt + 3);
  }
}

// ------------- N-inner (transpose-read) tile GEMM core for G ----------------
// SINGLE instantiation (round-9 fix).  A==B allowed (diag tiles stage twice —
// the B stage hits L2 lines the A stage just fetched).  Per K-step: stage
// [32 n][128 d] into LDS as [dblk 8][nblk 8][4 n][16 d] subtiles.  Read:
// per-lane vaddr = subtile_base + quad*256 + l16*8 (+mi*1024); 16-lane group
// fetches the 128B subtile row-major, HW transpose delivers lane l16 elem j =
// T[j][l16] = X[n = kt*32 + quad*8 + j][d = m0 + dblk*16 + l16]; offset:128
// gives n = quad*8 + 4..7.  k-order identical for A and B so any k-permutation
// cancels in the contraction.
__device__ __forceinline__ void gemm_tile_nt(const unsigned short* __restrict__ Xs,
                                             int m0, int n0, f32x4 (&acc)[4][4]) {
  constexpr int LPS = 4;
  constexpr int NK = 16;
  __shared__ unsigned short sA[3][128 * BK];
  __shared__ unsigned short sB[3][128 * BK];
  const int tid = threadIdx.x;
  const int lane = tid & 63;
  const int w = tid >> 6;
  const int wm = w >> 1, wn = w & 1;
  const int quad = lane >> 4, l16 = lane & 15;

#pragma unroll
  for (int mi = 0; mi < 4; mi++)
#pragma unroll
    for (int ni = 0; ni < 4; ni++) acc[mi][ni] = f32x4{0.f, 0.f, 0.f, 0.f};

  auto stage = [&](int bb, int kt) {
#pragma unroll
    for (int j = 0; j < 2; j++) {
      const int g = w * 128 + j * 64 + lane;   // LDS granule 0..511
      const int dblk = g >> 6;
      const int nblk = (g >> 3) & 7;
      const int nr = (g >> 1) & 3;
      const int half = g & 1;
      const int n = kt * 32 + nblk * 4 + nr;
      const int base = w * 128 + j * 64;       // wave-uniform LDS base
      gld16(Xs + (size_t)n * 512 + m0 + dblk * 16 + half * 8,
            (char*)sA[bb] + (size_t)base * 16);
      gld16(Xs + (size_t)n * 512 + n0 + dblk * 16 + half * 8,
            (char*)sB[bb] + (size_t)base * 16);
    }
  };

  auto compute = [&](int bb) {
    const unsigned int abase =
        (unsigned int)(uintptr_t)(&sA[bb][0]) + (unsigned int)(quad * 256 + l16 * 8);
    const unsigned int bbase =
        (unsigned int)(uintptr_t)(&sB[bb][0]) + (unsigned int)(quad * 256 + l16 * 8);
    u32x2 ra[4][2], rb[4][2];
#pragma unroll
    for (int mi = 0; mi < 4; mi++) {
      const unsigned int pa = abase + (unsigned int)((wm * 4 + mi) * 1024);
      asm volatile("ds_read_b64_tr_b16 %0, %1" : "=v"(ra[mi][0]) : "v"(pa));
      asm volatile("ds_read_b64_tr_b16 %0, %1 offset:128" : "=v"(ra[mi][1]) : "v"(pa));
    }
#pragma unroll
    for (int ni = 0; ni < 4; ni++) {
      const unsigned int pb = bbase + (unsigned int)((wn * 4 + ni) * 1024);
      asm volatile("ds_read_b64_tr_b16 %0, %1" : "=v"(rb[ni][0]) : "v"(pb));
      asm volatile("ds_read_b64_tr_b16 %0, %1 offset:128" : "=v"(rb[ni][1]) : "v"(pb));
    }
    asm volatile("s_waitcnt lgkmcnt(0)" ::: "memory");
    __builtin_amdgcn_sched_barrier(0);  // rule #18: pin consumers after the wait
    union U { unsigned int u[4]; bf16x8 v; };
    bf16x8 af[4], bfr[4];
#pragma unroll
    for (int mi = 0; mi < 4; mi++) {
      U ua;
      ua.u[0] = ra[mi][0][0]; ua.u[1] = ra[mi][0][1];
      ua.u[2] = ra[mi][1][0]; ua.u[3] = ra[mi][1][1];
      af[mi] = ua.v;
    }
#pragma unroll
    for (int ni = 0; ni < 4; ni++) {
      U ub;
      ub.u[0] = rb[ni][0][0]; ub.u[1] = rb[ni][0][1];
      ub.u[2] = rb[ni][1][0]; ub.u[3] = rb[ni][1][1];
      bfr[ni] = ub.v;
    }
    __builtin_amdgcn_s_setprio(1);
#pragma unroll
    for (int mi = 0; mi < 4; mi++)
#pragma unroll
      for (int ni = 0; ni < 4; ni++)
        acc[mi][ni] = __builtin_amdgcn_mfma_f32_16x16x32_bf16(af[mi], bfr[ni],
                                                              acc[mi][ni], 0, 0, 0);
    __builtin_amdgcn_s_setprio(0);
  };

  stage(0, 0);
  stage(1, 1);
  stage(2, 2);
#pragma unroll
  for (int kt = 0; kt < NK; ++kt) {
    if (kt < NK - 2) { vmw<2 * LPS>(); }
    else if (kt == NK - 2) { vmw<LPS>(); }
    else { vmw<0>(); }
    BAR;
    compute(kt % 3);
    BAR;
    if (kt < NK - 3) stage(kt % 3, kt + 3);
  }
}

// ---- prep: PURE streaming cast X fp32 -> Xb bf16.  Max TLP: 2048 blocks,
// zero LDS, zero atomics, zero tail.  8 independent 16B loads in flight.
__global__ __launch_bounds__(256) void prep_kernel(const float* __restrict__ X,
                                                   unsigned short* __restrict__ Xb) {
  const int t = threadIdx.x;
  const size_t base = (size_t)blockIdx.x * 8192;   // 2048 blocks x 8192 elems
  f32x4 v[8];
#pragma unroll
  for (int k = 0; k < 4; k++) {
    const size_t idx = base + (size_t)k * 2048 + (size_t)t * 8;
    v[2 * k] = *(const f32x4*)(X + idx);
    v[2 * k + 1] = *(const f32x4*)(X + idx + 4);
  }
  __builtin_amdgcn_sched_barrier(0);  // all 8 loads issued before any use
#pragma unroll
  for (int k = 0; k < 4; k++) {
    const size_t idx = base + (size_t)k * 2048 + (size_t)t * 8;
    u16x8 o;
#pragma unroll
    for (int j = 0; j < 4; j++) o[j] = f2bf(v[2 * k][j]);
#pragma unroll
    for (int j = 0; j < 4; j++) o[4 + j] = f2bf(v[2 * k + 1][j]);
    *(u16x8*)(Xb + idx) = o;
  }
}

// ---- W casts + zero-init of mean_x (runs before prep/g_gemm in-stream) ----
__global__ __launch_bounds__(256) void prep_w_kernel(const float* __restrict__ Wv,
                                                     const float* __restrict__ Wth,
                                                     unsigned short* __restrict__ Wvb,
                                                     unsigned short* __restrict__ Wtb,
                                                     float* __restrict__ mean_x) {
  const int blk = blockIdx.x;
  const int t = threadIdx.x;
  if (blk == 0) {
#pragma unroll
    for (int i = 0; i < 8; i++) mean_x[t + i * 256] = 0.f;
  }
  const float* src = (blk < 128) ? Wv : Wth;
  unsigned short* dst = (blk < 128) ? Wvb : Wtb;
  const int i = (blk & 127) * 256 + t;
  const f32x4* pp = (const f32x4*)(src + (size_t)i * 8);
  f32x4 v0 = pp[0], v1 = pp[1];
  u16x8 o;
  o[0] = f2bf(v0[0]); o[1] = f2bf(v0[1]); o[2] = f2bf(v0[2]); o[3] = f2bf(v0[3]);
  o[4] = f2bf(v1[0]); o[5] = f2bf(v1[1]); o[6] = f2bf(v1[2]); o[7] = f2bf(v1[3]);
  *(u16x8*)(dst + (size_t)i * 8) = o;
}

// ---- G = X^T X (per batch) from row-major Xb, split-K=16, upper tiles ----
// Grid (64, 11): t<10 = GEMM tiles; t==10 = colsum rider block for slice z.
static __device__ const int TI[10] = {0, 0, 0, 0, 1, 1, 1, 2, 2, 3};
static __device__ const int TJ[10] = {0, 1, 2, 3, 1, 2, 3, 2, 3, 3};

__global__ __launch_bounds__(256) void g_gemm_kernel(const unsigned short* __restrict__ Xb,
                                                     float* __restrict__ G_part,
                                                     float* __restrict__ mean_x) {
  const int t = blockIdx.y;        // 0..9 tile, 10 = colsum
  const int z = blockIdx.x;        // b*16 + s
  const int b = z >> 4, s = z & 15;
  const unsigned short* Xs = Xb + (size_t)(b * 8192 + s * 512) * 512;
  if (t == 10) {
    // colsum rider: 4 waves x 128 row-steps; lane l owns d-cols l*8..l*8+7
    const int w = threadIdx.x >> 6, l = threadIdx.x & 63;
    float cs[8] = {0.f, 0.f, 0.f, 0.f, 0.f, 0.f, 0.f, 0.f};
    for (int i0 = 0; i0 < 128; i0 += 8) {
      u16x8 val[8];
#pragma unroll
      for (int i = 0; i < 8; i++) {
        const int r = w + 4 * (i0 + i);
        val[i] = *(const u16x8*)(Xs + (size_t)r * 512 + l * 8);
      }
      __builtin_amdgcn_sched_barrier(0);
#pragma unroll
      for (int i = 0; i < 8; i++)
#pragma unroll
        for (int j = 0; j < 8; j++) cs[j] += bf2f(val[i][j]);
    }
#pragma unroll
    for (int j = 0; j < 8; j++)
      atomicAdd(&mean_x[b * 512 + l * 8 + j], cs[j]);
    return;
  }
  const int m0 = TI[t] * 128, n0 = TJ[t] * 128;
  f32x4 acc[4][4];
  gemm_tile_nt(Xs, m0, n0, acc);
  float* Cp = G_part + ((size_t)z * 10 + t) * 16384;  // tile stored [n_local][m_local]
  const int tid = threadIdx.x, lane = tid & 63, w = tid >> 6;
  const int wm = w >> 1, wn = w & 1, quad = lane >> 4, l16 = lane & 15;
#pragma unroll
  for (int mi = 0; mi < 4; mi++)
#pragma unroll
    for (int ni = 0; ni < 4; ni++) {
      const int ml = wm * 64 + mi * 16 + quad * 4;
      const int nl = wn * 64 + ni * 16 + l16;
      *(f32x4*)(Cp + (size_t)nl * 128 + ml) = acc[mi][ni];
    }
}

// sum slices, scale, cast bf16, write G + mirror.  Blocks >= 320: meanV part.
__global__ __launch_bounds__(256) void g_fin_kernel(const float* __restrict__ G_part,
                                                    unsigned short* __restrict__ Gb,
                                                    const float* __restrict__ mean_x,
                                                    const float* __restrict__ Wv,
                                                    float* __restrict__ meanV) {
  const int blk = blockIdx.x;  // 4*10*8 + 8
  if (blk >= 320) {
    const int idx = (blk - 320) * 256 + threadIdx.x;
    const int b = idx >> 9, e = idx & 511;
    const float* mx = mean_x + b * 512;
    const float* wr = Wv + (size_t)e * 512;
    float s = 0.f;
    for (int d = 0; d < 512; d += 4) {
      f32x4 a = *(const f32x4*)(mx + d);
      f32x4 w4 = *(const f32x4*)(wr + d);
      s += a[0] * w4[0] + a[1] * w4[1] + a[2] * w4[2] + a[3] * w4[3];
    }
    meanV[idx] = s * (1.f / 8192.f);
    return;
  }
  const int b = blk / 80, rem = blk % 80;
  const int t = rem >> 3, cc = rem & 7;
  const int i = TI[t], j = TJ[t];
  const int m0 = i * 128, n0 = j * 128;
  const int tid = threadIdx.x;
  const int np = cc * 16 + (tid >> 4);
  const int mp = (tid & 15) * 8;
  f32x4 s0 = f32x4{0.f, 0.f, 0.f, 0.f}, s1 = f32x4{0.f, 0.f, 0.f, 0.f};
#pragma unroll
  for (int s = 0; s < 16; s++) {
    const float* p = G_part + (((size_t)(b * 16 + s)) * 10 + t) * 16384 + (size_t)np * 128 + mp;
    s0 += *(const f32x4*)p;
    s1 += *(const f32x4*)(p + 4);
  }
  const float scale = (float)(1.0 / (8192.0 * 22.627416997969522));
  unsigned short h[8];
#pragma unroll
  for (int r = 0; r < 4; r++) { h[r] = f2bf(s0[r] * scale); h[r + 4] = f2bf(s1[r] * scale); }
  unsigned short* Gbb = Gb + (size_t)b * 262144;
#pragma unroll
  for (int r = 0; r < 8; r++)
    Gbb[(size_t)(m0 + mp + r) * 512 + (n0 + np)] = h[r];
  if (i != j) {
    u16x8 o;
#pragma unroll
    for (int r = 0; r < 8; r++) o[r] = h[r];
    *(u16x8*)(Gbb + (size_t)(n0 + np) * 512 + (m0 + mp)) = o;
  }
}

// small batched GEMM, row-major bf16 C: C[m][n] = sum_k A[m][k]B[n][k], all 512.
__global__ __launch_bounds__(256) void gemm_rm_kernel(const unsigned short* __restrict__ A,
                                                      const unsigned short* __restrict__ B,
                                                      unsigned short* __restrict__ C,
                                                      size_t Abs, size_t Bbs) {
  const int b = blockIdx.z;
  const int m0 = blockIdx.x * 64, n0 = blockIdx.y * 64;
  f32x4 acc[2][2];
  gemm_tile<64>(A + (size_t)b * Abs, 512, B + (size_t)b * Bbs, 512, m0, n0, acc);
  unsigned short* Cb = C + (size_t)b * 262144;
  const int tid = threadIdx.x, lane = tid & 63, w = tid >> 6;
  const int wm = w >> 1, wn = w & 1, quad = lane >> 4, l16 = lane & 15;
#pragma unroll
  for (int mi = 0; mi < 2; mi++)
#pragma unroll
    for (int ni = 0; ni < 2; ni++) {
      const int m = m0 + wm * 32 + mi * 16 + quad * 4;
      const int n = n0 + wn * 32 + ni * 16 + l16;
#pragma unroll
      for (int r = 0; r < 4; r++)
        Cb[(size_t)(m + r) * 512 + n] = f2bf(acc[mi][ni][r]);
    }
}

// final: out[m][e] = sum_d Xb[m][d]*kvt_b[e][d] + meanV[b][e]
__global__ __launch_bounds__(256) void gemm_out_kernel(
    const unsigned short* __restrict__ Xb, const unsigned short* __restrict__ kvt,
    const float* __restrict__ meanV, float* __restrict__ out) {
  const int D = blockIdx.x;                      // 0..1023
  const int gm = (D & 7) + ((D >> 5) << 3);      // m-tile 0..255
  const int nt = (D >> 3) & 3;                   // n-tile 0..3
  const int m0 = gm * 128, n0 = nt * 128;
  const int b = gm >> 6;
  const unsigned short* Bm = kvt + (size_t)b * 262144;
  f32x4 acc[4][4];
  gemm_tile<128>(Xb, 512, Bm, 512, m0, n0, acc);
  const int tid = threadIdx.x, lane = tid & 63, w = tid >> 6;
  const int wm = w >> 1, wn = w & 1, quad = lane >> 4, l16 = lane & 15;
#pragma unroll
  for (int ni = 0; ni < 4; ni++) {
    const int e = n0 + wn * 64 + ni * 16 + l16;
    const float mu = meanV[b * 512 + e];
#pragma unroll
    for (int mi = 0; mi < 4; mi++) {
      const int m = m0 + wm * 64 + mi * 16 + quad * 4;
#pragma unroll
      for (int r = 0; r < 4; r++)
        out[(size_t)(m + r) * 512 + e] = acc[mi][ni][r] + mu;
    }
  }
}

extern "C" void kernel_launch(void* const* d_in, const int* in_sizes, int n_in,
                              void* d_out, int out_size, void* d_ws, size_t ws_size,
                              hipStream_t stream) {
  const float* X = (const float*)d_in[0];
  const float* Wv = (const float*)d_in[1];
  const float* Wth = (const float*)d_in[2];
  float* out = (float*)d_out;
  char* ws = (char*)d_ws;

  unsigned short* Xb = (unsigned short*)(ws);                  // 32 MB
  float* G_part = (float*)(ws + 67108864ull);                  // 41.94 MB
  unsigned short* Gb = (unsigned short*)(ws + 109051904ull);   // 2 MB
  unsigned short* Ht = (unsigned short*)(ws + 111149056ull);   // 2 MB
  unsigned short* kvt = (unsigned short*)(ws + 113246208ull);  // 2 MB
  unsigned short* Wvb = (unsigned short*)(ws + 115343360ull);  // 0.5 MB
  unsigned short* Wtb = (unsigned short*)(ws + 115867648ull);  // 0.5 MB
  float* mean_x = (float*)(ws + 116391936ull);                 // 8 KB
  float* meanV = (float*)(ws + 116400128ull);                  // 8 KB

  prep_w_kernel<<<256, 256, 0, stream>>>(Wv, Wth, Wvb, Wtb, mean_x);
  prep_kernel<<<2048, 256, 0, stream>>>(X, Xb);

  g_gemm_kernel<<<dim3(64, 11), 256, 0, stream>>>(Xb, G_part, mean_x);
  g_fin_kernel<<<328, 256, 0, stream>>>(G_part, Gb, mean_x, Wv, meanV);

  gemm_rm_kernel<<<dim3(8, 8, 4), 256, 0, stream>>>(Wvb, Gb, Ht, 0, 262144);
  gemm_rm_kernel<<<dim3(8, 8, 4), 256, 0, stream>>>(Ht, Wtb, kvt, 262144, 0);

  gemm_out_kernel<<<1024, 256, 0, stream>>>(Xb, kvt, meanV, out);
}